// Round 5
// baseline (450.910 us; speedup 1.0000x reference)
//
#include <hip/hip_runtime.h>

// Part_CAM: only parts e=1..4 survive feat_cam[:,1:].
// Row-0-of-chain: e0^T * (sub[11] @ ... @ sub[0]) as 12 vec-mat products.
// Round 5: K1 = chains with 512-thread blocks, launch_bounds(512,2) -> 256
// VGPR cap, full per-layer row hoist (xs[99] for p=0, xs[25] for p>=1),
// cross-layer prefetch under lgkm-only barriers. K2 = epilogue (w x relu(F))
// as its own kernel: 768 blocks, balanced across all CUs, no reg pressure
// on K1. w passes through d_ws.

#define L_ 12
#define B_ 64
#define N_ 201
#define D_ 768

// barrier that does NOT drain vmcnt: prefetched global loads stay in flight
#define BARRIER_LGKM() do { \
    asm volatile("s_waitcnt lgkmcnt(0)" ::: "memory"); \
    __builtin_amdgcn_s_barrier(); \
} while (0)

template<int RP, int CW, int RGS>
__device__ __forceinline__ const float* run_chain(
    const float* __restrict__ x, int b, int e, int s, int M,
    float* vin, float* vout, float* vpart, int tid)
{
    const int c   = tid % CW;
    const int rg  = tid / CW;                 // wave-uniform
    const int colc = (c < M) ? c : (M - 1);   // clamp pad lanes (dup loads ok)
    const int mycol = (colc == 0) ? e : (s + colc - 1);
    const int r0  = rg * RP;
    const size_t mat_elems = (size_t)N_ * N_;

    float xs[RP];

    // prefetch layer 10
    {
        const float* colp = x + ((size_t)10 * B_ + b) * mat_elems + mycol;
        #pragma unroll
        for (int j = 0; j < RP; ++j) {
            const int rr = r0 + j;
            const int rc = (rr < M) ? rr : (M - 1);
            const int ra = (rc == 0) ? e : (s + rc - 1);
            xs[j] = colp[(size_t)ra * N_];
        }
    }

    for (int l = 10; l >= 0; --l) {
        // FMA current layer. vin tail beyond M is zero -> unguarded reads ok.
        float ac0 = 0.f, ac1 = 0.f, ac2 = 0.f, ac3 = 0.f;
        #pragma unroll
        for (int j = 0; j < RP; ++j) {
            const float prod = vin[r0 + j] * xs[j];
            if ((j & 3) == 0) ac0 += prod;
            else if ((j & 3) == 1) ac1 += prod;
            else if ((j & 3) == 2) ac2 += prod;
            else ac3 += prod;
        }
        const float acc = (ac0 + ac1) + (ac2 + ac3);
        // issue next layer's loads now; they stay in flight across barriers
        if (l > 0) {
            const float* colp = x + ((size_t)(l - 1) * B_ + b) * mat_elems + mycol;
            #pragma unroll
            for (int j = 0; j < RP; ++j) {
                const int rr = r0 + j;
                const int rc = (rr < M) ? rr : (M - 1);
                const int ra = (rc == 0) ? e : (s + rc - 1);
                xs[j] = colp[(size_t)ra * N_];
            }
        }
        vpart[rg * CW + c] = acc;
        BARRIER_LGKM();
        if (tid < M) {
            float sum = 0.f;
            #pragma unroll
            for (int g = 0; g < RGS; ++g) sum += vpart[g * CW + tid];
            vout[tid] = sum;
        }
        BARRIER_LGKM();
        float* t = vin; vin = vout; vout = t;
    }
    return vin;
}

__global__ __launch_bounds__(512, 2) void part_cam_chain(
    const float* __restrict__ x,     // (L, B, N, N)
    float* __restrict__ w)           // ws: (4, B, 256)
{
    const int p = blockIdx.x >> 6;   // 0..3; p=0 blocks dispatch first
    const int b = blockIdx.x & 63;
    const int e = p + 1;
    const int s = (p == 0) ? 5 : (p == 1) ? 5 : (p == 2) ? 54 : 103;
    const int t = (p == 0) ? 201 : (p == 1) ? 103 : (p == 2) ? 152 : 201;
    const int K = t - s;
    const int M = K + 1;             // 197 or 99
    const int tid = threadIdx.x;

    __shared__ float bufA[256];
    __shared__ float bufB[256];
    __shared__ float vpart[512];

    if (tid < 256) { bufA[tid] = 0.f; bufB[tid] = 0.f; }
    if (tid < M) {
        const float* m11 = x + ((size_t)11 * B_ + b) * (size_t)(N_ * N_);
        bufA[tid] = m11[(size_t)e * N_ + ((tid == 0) ? e : (s + tid - 1))];
    }
    BARRIER_LGKM();

    const float* vr;
    if (p == 0) vr = run_chain<99, 256, 2>(x, b, e, s, M, bufA, bufB, vpart, tid);
    else        vr = run_chain<25, 128, 4>(x, b, e, s, M, bufA, bufB, vpart, tid);

    if (tid < K) w[((size_t)p * B_ + b) * 256 + tid] = vr[1 + tid];
}

__global__ __launch_bounds__(256) void part_cam_epi(
    const float* __restrict__ feat,  // (B, N, D)
    const float* __restrict__ w,     // ws: (4, B, 256)
    float* __restrict__ out)         // (B, 4, D)
{
    const int blk = blockIdx.x;      // b*12 + p*3 + dc
    const int b  = blk / 12;
    const int rem = blk % 12;
    const int p  = rem / 3;
    const int dc = rem % 3;
    const int s = (p == 0) ? 5 : (p == 1) ? 5 : (p == 2) ? 54 : 103;
    const int t = (p == 0) ? 201 : (p == 1) ? 103 : (p == 2) ? 152 : 201;
    const int K = t - s;
    const int tid = threadIdx.x;

    __shared__ float wsh[256];
    wsh[tid] = w[((size_t)p * B_ + b) * 256 + tid];
    __syncthreads();

    const int d = dc * 256 + tid;
    const float* fb = feat + (size_t)b * N_ * D_ + d;
    float acc = 0.f;
    for (int k = 0; k < K; k += 16) {
        float f[16];
        #pragma unroll
        for (int j = 0; j < 16; ++j) {
            if (k + j < K) f[j] = fb[(size_t)(s + k + j) * D_];
        }
        #pragma unroll
        for (int j = 0; j < 16; ++j) {
            if (k + j < K) acc += wsh[k + j] * fmaxf(f[j], 0.f);
        }
    }
    out[((size_t)b * 4 + p) * D_ + d] = acc;
}

extern "C" void kernel_launch(void* const* d_in, const int* in_sizes, int n_in,
                              void* d_out, int out_size, void* d_ws, size_t ws_size,
                              hipStream_t stream) {
    const float* x    = (const float*)d_in[0];
    const float* feat = (const float*)d_in[1];
    float* out = (float*)d_out;
    float* w   = (float*)d_ws;       // 4*64*256 floats = 256 KiB
    part_cam_chain<<<dim3(256), dim3(512), 0, stream>>>(x, w);
    part_cam_epi<<<dim3(768), dim3(256), 0, stream>>>(feat, w, out);
}

// Round 7
// 87.642 us; speedup vs baseline: 5.1449x; 5.1449x over previous
//
#include <hip/hip_runtime.h>

// Part_CAM: only parts e=1..4 survive feat_cam[:,1:].
// Row-0-of-chain: e0^T * (sub[11] @ ... @ sub[0]) as 12 vec-mat products.
// Round 7: same global_load_lds ring as round 6 with the ring-slot bug fixed:
// issue writes into slot (sl + LEAD) % RING (the free slot LEAD ahead), so the
// consume pointer (mod RING) meets each row's data exactly. Round 6 wrote into
// the just-consumed slot, leaving slot 5 never written -> garbage reads.

#define L_ 12
#define B_ 64
#define N_ 201
#define D_ 768
#define NN_ ((size_t)N_ * N_)

#define RING 6
#define LEAD 5

// compiler+HW barrier that drains LDS ops but NOT vmcnt (prefetch survives)
#define BAR() asm volatile("s_waitcnt lgkmcnt(0)\n\ts_barrier" ::: "memory")
#define WAITC(n) asm volatile("s_waitcnt vmcnt(" #n ")" ::: "memory")

__device__ __forceinline__ void glds4(const float* g, float* l) {
    __builtin_amdgcn_global_load_lds(
        (const __attribute__((address_space(1))) void*)g,
        (__attribute__((address_space(3))) void*)l, 4, 0, 0);
}

// RP rows per wave; NQ = 64-lane 4B chunks per row (4 -> 256 cols, 2 -> 128).
// Slot physical stride fixed at 256 floats.
template<int RP, int NQ>
__device__ __forceinline__ float* run_chain(
    const float* __restrict__ x, int b, int e, int s, int M,
    float* vin, float* vout, float* ring, float* vpart, float* partial,
    int tid)
{
    const int lane = tid & 63;
    const int wr   = tid >> 6;            // 0..15 row-group (wave-uniform)
    const int QT   = NQ * 64;             // valid floats per slot

    // per-lane column element-offsets within a row, per chunk.
    // q = i*64+lane; q==0 -> e-column; else col s-1+min(q, M-1).
    int cadd[4];
    #pragma unroll
    for (int i = 0; i < NQ; ++i) {
        int q  = i * 64 + lane;
        int qc = (q < M) ? q : (M - 1);
        cadd[i] = (q == 0) ? e : (s - 1 + qc);
    }

    // issue one slot: NQ async row-chunk loads for row-cursor ji into slot isl
    auto ISSUE = [&](const float* xl, int ji, int isl) {
        int rr = wr * RP + ji;
        int rc = (rr < M) ? rr : (M - 1);
        int ra = (rc == 0) ? e : (s + rc - 1);
        const float* rowp = xl + (size_t)ra * N_;
        float* sb = ring + (size_t)(wr * RING + isl) * 256;
        #pragma unroll
        for (int i = 0; i < NQ; ++i)
            glds4(rowp + cadd[i], sb + i * 64);
    };

    // prologue: issue LEAD slots of layer 10 into slots 0..LEAD-1
    const float* xli = x + ((size_t)10 * B_ + b) * NN_;
    #pragma unroll
    for (int g = 0; g < LEAD; ++g) ISSUE(xli, g, g);
    int ji = LEAD;
    int sl = 0;   // consume slot cursor

    BAR();   // gather stores to vin visible

    float a0 = 0.f, a1 = 0.f, a2 = 0.f, a3 = 0.f;

    auto CONSUME = [&](int j) {
        const float* sb = ring + (size_t)(wr * RING + sl) * 256;
        float vj = vin[wr * RP + j];
        if (NQ == 4) {
            float4 mv = *(const float4*)(sb + lane * 4);
            a0 += vj * mv.x; a1 += vj * mv.y; a2 += vj * mv.z; a3 += vj * mv.w;
        } else {
            float2 mv = *(const float2*)(sb + lane * 2);
            a0 += vj * mv.x; a1 += vj * mv.y;
        }
    };

    auto REDUCE = [&]() {
        if (NQ == 4)
            *(float4*)&vpart[(wr << 8) + (lane << 2)] = make_float4(a0, a1, a2, a3);
        else
            *(float2*)&vpart[wr * 128 + lane * 2] = make_float2(a0, a1);
        BAR();
        if (NQ == 4) {
            int tg = tid >> 8, q = tid & 255;
            partial[tg * 256 + q] =
                vpart[(tg * 4 + 0) * 256 + q] + vpart[(tg * 4 + 1) * 256 + q] +
                vpart[(tg * 4 + 2) * 256 + q] + vpart[(tg * 4 + 3) * 256 + q];
        } else {
            int tg = tid >> 7, q = tid & 127;
            partial[tg * 128 + q] =
                vpart[(tg * 2 + 0) * 128 + q] + vpart[(tg * 2 + 1) * 128 + q];
        }
        BAR();
        if (tid < QT) {
            float v = 0.f;
            if (NQ == 4) {
                v = partial[tid] + partial[256 + tid] + partial[512 + tid] + partial[768 + tid];
            } else {
                #pragma unroll
                for (int g = 0; g < 8; ++g) v += partial[g * 128 + tid];
            }
            vout[tid] = (tid < M) ? v : 0.f;   // q == c mapping; q=0 is e-col
        }
        BAR();
        float* t = vin; vin = vout; vout = t;
        a0 = a1 = a2 = a3 = 0.f;
    };

    // layers 10..1: constant counted wait (oldest slot arrived), always issue
    for (int l = 10; l >= 1; --l) {
        #pragma unroll
        for (int j = 0; j < RP; ++j) {
            if (NQ == 4) { WAITC(16); } else { WAITC(8); }
            CONSUME(j);
            {
                int isl = sl + LEAD; if (isl >= RING) isl -= RING;
                ISSUE(xli, ji, isl);
            }
            ji++;
            if (ji == RP) { ji = 0; xli -= (size_t)B_ * NN_; }
            sl = (sl + 1 == RING) ? 0 : sl + 1;
        }
        REDUCE();
    }

    // final layer (l=0): issues stop; drain once when pipeline empties
    #pragma unroll
    for (int j = 0; j < RP; ++j) {
        if (j < RP - LEAD) {
            if (NQ == 4) { WAITC(16); } else { WAITC(8); }
        } else if (j == RP - LEAD) {
            WAITC(0);
        }
        CONSUME(j);
        if (j < RP - LEAD) {
            int isl = sl + LEAD; if (isl >= RING) isl -= RING;
            ISSUE(xli, ji, isl);
            ji++;
        }
        sl = (sl + 1 == RING) ? 0 : sl + 1;
    }
    REDUCE();
    return vin;
}

__global__ __launch_bounds__(1024) void part_cam_chain(
    const float* __restrict__ x,     // (L, B, N, N)
    const float* __restrict__ feat,  // (B, N, D)
    float* __restrict__ out,         // (B, 4, D)
    float* __restrict__ wbuf)        // ws: (B, 256) for p=0
{
    __shared__ __align__(16) float ring[16 * RING * 256];  // 96 KB
    __shared__ __align__(16) float vpart[16 * 256];        // 16 KB
    __shared__ __align__(16) float partial[1024];          // 4 KB
    __shared__ __align__(16) float bufA[256];
    __shared__ __align__(16) float bufB[256];

    const int p = blockIdx.x >> 6;   // 0..3  (part e = p+1)
    const int b = blockIdx.x & 63;
    const int e = p + 1;
    const int s = (p == 0) ? 5 : (p == 1) ? 5 : (p == 2) ? 54 : 103;
    const int t = (p == 0) ? 201 : (p == 1) ? 103 : (p == 2) ? 152 : 201;
    const int K = t - s;
    const int M = K + 1;             // 197 or 99
    const int tid = threadIdx.x;

    // zero v buffers (tails must stay 0), gather row e of sub[11]
    if (tid < 256) { bufA[tid] = 0.f; bufB[tid] = 0.f; }
    if (tid < M) {
        const float* m11 = x + ((size_t)11 * B_ + b) * NN_;
        bufA[tid] = m11[(size_t)e * N_ + ((tid == 0) ? e : (s + tid - 1))];
    }
    // (run_chain issues prologue then BARs; gather stores drained there)

    float* vf = (p == 0)
        ? run_chain<13, 4>(x, b, e, s, M, bufA, bufB, ring, vpart, partial, tid)
        : run_chain<7, 2>(x, b, e, s, M, bufA, bufB, ring, vpart, partial, tid);

    if (p == 0) {
        if (tid < 256) wbuf[b * 256 + tid] = (tid >= 1 && tid <= K) ? vf[tid] : 0.f;
    } else {
        // inline epilogue: out[b,p,d] = sum_k vf[1+k] * relu(feat[b,s+k,d])
        if (tid < D_) {
            const float* fb = feat + (size_t)b * N_ * D_ + tid;
            float acc = 0.f;
            for (int k = 0; k < 98; k += 8) {
                float f[8];
                #pragma unroll
                for (int jj = 0; jj < 8; ++jj)
                    if (k + jj < K) f[jj] = fb[(size_t)(s + k + jj) * D_];
                #pragma unroll
                for (int jj = 0; jj < 8; ++jj)
                    if (k + jj < K) acc += vf[1 + k + jj] * fmaxf(f[jj], 0.f);
            }
            out[((size_t)b * 4 + p) * D_ + tid] = acc;
        }
    }
}

__global__ __launch_bounds__(256) void part_cam_epi0(
    const float* __restrict__ feat,  // (B, N, D)
    const float* __restrict__ wbuf,  // (B, 256), w at [1..196]
    float* __restrict__ out)         // (B, 4, D)
{
    const int b  = blockIdx.x / 3;
    const int dc = blockIdx.x % 3;
    const int tid = threadIdx.x;
    __shared__ float wsh[256];
    wsh[tid] = wbuf[b * 256 + tid];
    __syncthreads();
    const int d = dc * 256 + tid;
    const float* fb = feat + (size_t)b * N_ * D_ + d;
    float acc = 0.f;
    for (int k = 0; k < 196; k += 16) {
        float f[16];
        #pragma unroll
        for (int jj = 0; jj < 16; ++jj)
            if (k + jj < 196) f[jj] = fb[(size_t)(5 + k + jj) * D_];
        #pragma unroll
        for (int jj = 0; jj < 16; ++jj)
            if (k + jj < 196) acc += wsh[1 + k + jj] * fmaxf(f[jj], 0.f);
    }
    out[((size_t)b * 4 + 0) * D_ + d] = acc;
}

extern "C" void kernel_launch(void* const* d_in, const int* in_sizes, int n_in,
                              void* d_out, int out_size, void* d_ws, size_t ws_size,
                              hipStream_t stream) {
    const float* x    = (const float*)d_in[0];
    const float* feat = (const float*)d_in[1];
    float* out = (float*)d_out;
    float* w   = (float*)d_ws;   // 64*256 floats = 64 KiB
    part_cam_chain<<<dim3(256), dim3(1024), 0, stream>>>(x, feat, out, w);
    part_cam_epi0<<<dim3(192), dim3(256), 0, stream>>>(feat, w, out);
}